// Round 1
// baseline (855.851 us; speedup 1.0000x reference)
//
#include <hip/hip_runtime.h>

#define N_NODES 10000
#define E_EDGES 320000

// ---------------- degree / CSR construction ----------------

__global__ void k_hist(const int* __restrict__ dst, int* __restrict__ deg) {
    int e = blockIdx.x * blockDim.x + threadIdx.x;
    if (e < E_EDGES) atomicAdd(&deg[dst[e]], 1);
}

__global__ void k_dinv(const int* __restrict__ deg, float* __restrict__ dinv) {
    int i = blockIdx.x * blockDim.x + threadIdx.x;
    if (i < N_NODES) dinv[i] = rsqrtf(1.0f + (float)deg[i]);  // +1 self-loop
}

// single-block exclusive scan of deg -> row offsets (N=10000, 256 thr x 40 elems)
__global__ void k_scan(const int* __restrict__ deg, int* __restrict__ roff) {
    __shared__ int sums[256];
    __shared__ int offs[256];
    const int CH = 40;
    int t = threadIdx.x;
    int base = t * CH;
    int s = 0;
    for (int i = 0; i < CH; i++) {
        int idx = base + i;
        if (idx < N_NODES) s += deg[idx];
    }
    sums[t] = s;
    __syncthreads();
    if (t == 0) {
        int r = 0;
        for (int i = 0; i < 256; i++) { offs[i] = r; r += sums[i]; }
    }
    __syncthreads();
    int r = offs[t];
    for (int i = 0; i < CH; i++) {
        int idx = base + i;
        if (idx < N_NODES) { roff[idx] = r; r += deg[idx]; }
    }
    if (t == 255) roff[N_NODES] = E_EDGES;
}

__global__ void k_scatter(const int* __restrict__ src, const int* __restrict__ dst,
                          const int* __restrict__ roff, int* __restrict__ cursor,
                          const float* __restrict__ dinv,
                          int* __restrict__ csrc, float* __restrict__ cw) {
    int e = blockIdx.x * blockDim.x + threadIdx.x;
    if (e >= E_EDGES) return;
    int s = src[e], d = dst[e];
    int slot = roff[d] + atomicAdd(&cursor[d], 1);
    csrc[slot] = s;
    cw[slot] = dinv[s] * dinv[d];
}

// ---------------- GEMM1: [10000 x 10000] @ [10000 x 64], fp32, split-K atomic ----------------

#define G1_BM 128
#define G1_BK 32
#define G1_CHUNK 1280  // 8 chunks cover K=10000 (last = 1040); multiple of 32

__global__ void k_gemm1(const float* __restrict__ x, const float* __restrict__ W1,
                        float* __restrict__ out) {
    __shared__ float As[G1_BK][G1_BM + 4];  // [k][m], padded
    __shared__ float Bs[G1_BK][64];         // [k][c]
    int tid = threadIdx.x;
    int tx = tid & 15;   // 4 cols each -> 64 cols
    int ty = tid >> 4;   // 8 rows each -> 128 rows
    int m0 = blockIdx.x * G1_BM;
    int ks = blockIdx.y * G1_CHUNK;
    int ke = min(ks + G1_CHUNK, N_NODES);
    float acc[8][4] = {};

    for (int k0 = ks; k0 < ke; k0 += G1_BK) {
        // A tile: 128 rows x 32 k = 1024 float4, transposed into As[k][m]
        for (int f = tid; f < 1024; f += 256) {
            int row = f >> 3;
            int kq = f & 7;
            int gm = m0 + row, gk = k0 + kq * 4;
            float4 v = make_float4(0.f, 0.f, 0.f, 0.f);
            if (gm < N_NODES && gk < ke)  // ke % 4 == 0 so full float4 is in-range
                v = *(const float4*)(x + (long)gm * N_NODES + gk);
            As[kq * 4 + 0][row] = v.x;
            As[kq * 4 + 1][row] = v.y;
            As[kq * 4 + 2][row] = v.z;
            As[kq * 4 + 3][row] = v.w;
        }
        // B tile: 32 k x 64 c = 512 float4
        for (int f = tid; f < 512; f += 256) {
            int kk = f >> 4, cq = f & 15;
            int gk = k0 + kk;
            float4 v = make_float4(0.f, 0.f, 0.f, 0.f);
            if (gk < ke) v = *(const float4*)(W1 + (long)gk * 64 + cq * 4);
            *(float4*)&Bs[kk][cq * 4] = v;
        }
        __syncthreads();

        for (int kk = 0; kk < G1_BK; kk++) {
            float4 b4 = *(const float4*)&Bs[kk][tx * 4];
            float4 a0 = *(const float4*)&As[kk][ty * 8];
            float4 a1 = *(const float4*)&As[kk][ty * 8 + 4];
            float ar[8] = {a0.x, a0.y, a0.z, a0.w, a1.x, a1.y, a1.z, a1.w};
            float br[4] = {b4.x, b4.y, b4.z, b4.w};
#pragma unroll
            for (int i = 0; i < 8; i++)
#pragma unroll
                for (int j = 0; j < 4; j++)
                    acc[i][j] = fmaf(ar[i], br[j], acc[i][j]);
        }
        __syncthreads();
    }

#pragma unroll
    for (int i = 0; i < 8; i++) {
        int gm = m0 + ty * 8 + i;
        if (gm < N_NODES) {
            float* o = out + gm * 64 + tx * 4;
            atomicAdd(o + 0, acc[i][0]);
            atomicAdd(o + 1, acc[i][1]);
            atomicAdd(o + 2, acc[i][2]);
            atomicAdd(o + 3, acc[i][3]);
        }
    }
}

// ---------------- small GEMMs ----------------

// [10000 x 64] @ [64 x 64]; 4 rows/block, 256 threads (tx=col, ty=row)
__global__ void k_gemm64(const float* __restrict__ in, const float* __restrict__ W,
                         float* __restrict__ out) {
    __shared__ float Ws[64 * 64];
    __shared__ float Ain[4][64];
    int tid = threadIdx.x;
    int tx = tid & 63, ty = tid >> 6;
    for (int f = tid; f < 1024; f += 256)
        *(float4*)&Ws[f * 4] = *(const float4*)&W[f * 4];
    int gm = blockIdx.x * 4 + ty;
    Ain[ty][tx] = in[gm * 64 + tx];
    __syncthreads();
    float acc = 0.f;
#pragma unroll
    for (int k = 0; k < 64; k++) acc = fmaf(Ain[ty][k], Ws[k * 64 + tx], acc);
    out[gm * 64 + tx] = acc;
}

// [10000 x 64] @ [64 x 16]; 16 rows/block, 256 threads (tx=col 0..15, ty=row 0..15)
__global__ void k_gemm16(const float* __restrict__ in, const float* __restrict__ W,
                         float* __restrict__ out) {
    __shared__ float Ws[64 * 16];
    __shared__ float Ain[16][64];
    int tid = threadIdx.x;
    int tx = tid & 15, ty = tid >> 4;
    *(float4*)&Ws[tid * 4] = *(const float4*)&W[tid * 4];  // 1024 floats = 256 f4
    {
        int r = tid >> 4, kq = tid & 15;
        *(float4*)&Ain[r][kq * 4] =
            *(const float4*)(in + (long)(blockIdx.x * 16 + r) * 64 + kq * 4);
    }
    __syncthreads();
    float acc = 0.f;
#pragma unroll
    for (int k = 0; k < 64; k++) acc = fmaf(Ain[ty][k], Ws[k * 16 + tx], acc);
    out[(blockIdx.x * 16 + ty) * 16 + tx] = acc;
}

// ---------------- aggregation (one wave per node, 64 cols) ----------------

__global__ void k_agg64(const float* __restrict__ h, const float* __restrict__ bias,
                        const int* __restrict__ roff, const int* __restrict__ csrc,
                        const float* __restrict__ cw, const float* __restrict__ dinv,
                        float* __restrict__ out, int do_relu) {
    int n = blockIdx.x * 4 + (threadIdx.x >> 6);
    int c = threadIdx.x & 63;
    float di = dinv[n];
    float acc = di * di * h[n * 64 + c];  // self-loop
    int e0 = roff[n], e1 = roff[n + 1];
    for (int e = e0; e < e1; e++)
        acc = fmaf(cw[e], h[csrc[e] * 64 + c], acc);
    acc += bias[c];
    if (do_relu) acc = fmaxf(acc, 0.f);
    out[n * 64 + c] = acc;
}

// final aggregation (16 cols) + bias + softmax; one wave per node, 4 edge groups
__global__ void k_agg16_softmax(const float* __restrict__ h, const float* __restrict__ b3,
                                const int* __restrict__ roff, const int* __restrict__ csrc,
                                const float* __restrict__ cw, const float* __restrict__ dinv,
                                float* __restrict__ out) {
    int lane = threadIdx.x & 63;
    int n = blockIdx.x * 4 + (threadIdx.x >> 6);
    int c = lane & 15, g = lane >> 4;
    float di = dinv[n];
    float acc = (g == 0) ? di * di * h[n * 16 + c] : 0.f;
    int e0 = roff[n], e1 = roff[n + 1];
    for (int e = e0 + g; e < e1; e += 4)
        acc = fmaf(cw[e], h[csrc[e] * 16 + c], acc);
    acc += __shfl_xor(acc, 16);
    acc += __shfl_xor(acc, 32);
    float logit = acc + b3[c];
    float m = logit;
    m = fmaxf(m, __shfl_xor(m, 1));
    m = fmaxf(m, __shfl_xor(m, 2));
    m = fmaxf(m, __shfl_xor(m, 4));
    m = fmaxf(m, __shfl_xor(m, 8));
    float ex = expf(logit - m);
    float s = ex;
    s += __shfl_xor(s, 1);
    s += __shfl_xor(s, 2);
    s += __shfl_xor(s, 4);
    s += __shfl_xor(s, 8);
    if (g == 0) out[n * 16 + c] = ex / s;
}

// ---------------- launch ----------------

extern "C" void kernel_launch(void* const* d_in, const int* in_sizes, int n_in,
                              void* d_out, int out_size, void* d_ws, size_t ws_size,
                              hipStream_t stream) {
    (void)in_sizes; (void)n_in; (void)out_size; (void)ws_size;
    const float* x  = (const float*)d_in[0];
    const int*   ei = (const int*)d_in[1];
    const float* W1 = (const float*)d_in[2];
    const float* b1 = (const float*)d_in[3];
    const float* W2 = (const float*)d_in[4];
    const float* b2 = (const float*)d_in[5];
    const float* W3 = (const float*)d_in[6];
    const float* b3 = (const float*)d_in[7];
    float* out = (float*)d_out;
    const int* esrc = ei;
    const int* edst = ei + E_EDGES;

    char* p = (char*)d_ws;
    size_t off = 0;
    auto alloc = [&](size_t b) -> void* {
        void* r = p + off;
        off += (b + 255) & ~(size_t)255;
        return r;
    };
    int*   deg    = (int*)alloc(N_NODES * 4);
    int*   cursor = (int*)alloc(N_NODES * 4);
    int*   roff   = (int*)alloc((N_NODES + 1) * 4);
    float* dinv   = (float*)alloc(N_NODES * 4);
    int*   csrc   = (int*)alloc(E_EDGES * 4);
    float* cw     = (float*)alloc(E_EDGES * 4);
    float* bufA   = (float*)alloc(N_NODES * 64 * 4);
    float* bufB   = (float*)alloc(N_NODES * 64 * 4);
    float* bufC   = (float*)alloc(N_NODES * 16 * 4);

    hipMemsetAsync(deg, 0, N_NODES * 4, stream);
    hipMemsetAsync(cursor, 0, N_NODES * 4, stream);
    hipMemsetAsync(bufA, 0, N_NODES * 64 * 4, stream);  // gemm1 atomic accumulator

    k_hist<<<(E_EDGES + 255) / 256, 256, 0, stream>>>(edst, deg);
    k_dinv<<<(N_NODES + 255) / 256, 256, 0, stream>>>(deg, dinv);
    k_scan<<<1, 256, 0, stream>>>(deg, roff);
    k_scatter<<<(E_EDGES + 255) / 256, 256, 0, stream>>>(esrc, edst, roff, cursor, dinv,
                                                         csrc, cw);

    // layer 1
    k_gemm1<<<dim3((N_NODES + G1_BM - 1) / G1_BM, 8), 256, 0, stream>>>(x, W1, bufA);
    k_agg64<<<N_NODES / 4, 256, 0, stream>>>(bufA, b1, roff, csrc, cw, dinv, bufB, 1);
    // layer 2
    k_gemm64<<<N_NODES / 4, 256, 0, stream>>>(bufB, W2, bufA);
    k_agg64<<<N_NODES / 4, 256, 0, stream>>>(bufA, b2, roff, csrc, cw, dinv, bufB, 1);
    // layer 3 + softmax
    k_gemm16<<<N_NODES / 16, 256, 0, stream>>>(bufB, W3, bufC);
    k_agg16_softmax<<<N_NODES / 4, 256, 0, stream>>>(bufC, b3, roff, csrc, cw, dinv, out);
}

// Round 2
// 716.818 us; speedup vs baseline: 1.1940x; 1.1940x over previous
//
#include <hip/hip_runtime.h>

#define N_NODES 10000
#define E_EDGES 320000
#define KP 10016  // K padded to multiple of 32 for W split

typedef float f32x4 __attribute__((ext_vector_type(4)));
typedef __bf16 bf16x8 __attribute__((ext_vector_type(8)));

static __device__ __forceinline__ ushort f2bf(float f) {
    unsigned u = __float_as_uint(f);
    unsigned r = (u + 0x7fffu + ((u >> 16) & 1u)) >> 16;  // RNE
    return (ushort)r;
}
static __device__ __forceinline__ float bf2f(ushort h) {
    return __uint_as_float(((unsigned)h) << 16);
}

// ---------------- degree / CSR construction ----------------

__global__ void k_hist(const int* __restrict__ dst, int* __restrict__ deg) {
    int e = blockIdx.x * blockDim.x + threadIdx.x;
    if (e < E_EDGES) atomicAdd(&deg[dst[e]], 1);
}

__global__ void k_dinv(const int* __restrict__ deg, float* __restrict__ dinv) {
    int i = blockIdx.x * blockDim.x + threadIdx.x;
    if (i < N_NODES) dinv[i] = rsqrtf(1.0f + (float)deg[i]);  // +1 self-loop
}

__global__ void k_scan(const int* __restrict__ deg, int* __restrict__ roff) {
    __shared__ int sums[256];
    __shared__ int offs[256];
    const int CH = 40;
    int t = threadIdx.x;
    int base = t * CH;
    int s = 0;
    for (int i = 0; i < CH; i++) {
        int idx = base + i;
        if (idx < N_NODES) s += deg[idx];
    }
    sums[t] = s;
    __syncthreads();
    if (t == 0) {
        int r = 0;
        for (int i = 0; i < 256; i++) { offs[i] = r; r += sums[i]; }
    }
    __syncthreads();
    int r = offs[t];
    for (int i = 0; i < CH; i++) {
        int idx = base + i;
        if (idx < N_NODES) { roff[idx] = r; r += deg[idx]; }
    }
    if (t == 255) roff[N_NODES] = E_EDGES;
}

__global__ void k_scatter(const int* __restrict__ src, const int* __restrict__ dst,
                          const int* __restrict__ roff, int* __restrict__ cursor,
                          const float* __restrict__ dinv,
                          int* __restrict__ csrc, float* __restrict__ cw) {
    int e = blockIdx.x * blockDim.x + threadIdx.x;
    if (e >= E_EDGES) return;
    int s = src[e], d = dst[e];
    int slot = roff[d] + atomicAdd(&cursor[d], 1);
    csrc[slot] = s;
    cw[slot] = dinv[s] * dinv[d];
}

// ---------------- W1 split: fp32 [10000x64] -> bf16 hi/lo transposed [64][KP] ----------------

__global__ void k_wsplit(const float* __restrict__ W1, ushort* __restrict__ Whi,
                         ushort* __restrict__ Wlo) {
    int k = blockIdx.x * 256 + threadIdx.x;
    int n = blockIdx.y;
    if (k >= KP) return;
    ushort h = 0, l = 0;
    if (k < N_NODES) {
        float f = W1[(long)k * 64 + n];
        h = f2bf(f);
        l = f2bf(f - bf2f(h));
    }
    Whi[(long)n * KP + k] = h;
    Wlo[(long)n * KP + k] = l;
}

// ---------------- GEMM1: split-bf16 MFMA, [10000x10000]@[10000x64], split-K atomic ----------------

#define G1_BM 128
#define G1_CHUNK 1280  // 8 chunks; internal boundaries multiple of 32

__global__ __launch_bounds__(256) void k_gemm1_mfma(
        const float* __restrict__ x, const ushort* __restrict__ Whi,
        const ushort* __restrict__ Wlo, float* __restrict__ out) {
    // LDS rows padded 32 -> 40 ushorts (80 B) to break 64B-stride bank conflicts
    __shared__ ushort As[2][G1_BM][40];  // [hi/lo][m][k]
    __shared__ ushort Bs[2][64][40];     // [hi/lo][n][k]

    int tid = threadIdx.x;
    int lane = tid & 63, wv = tid >> 6;
    int quad = lane >> 4, lm = lane & 15;
    int q8 = quad * 8;
    int m0 = blockIdx.x * G1_BM;
    int ks = blockIdx.y * G1_CHUNK;
    int ke = min(ks + G1_CHUNK, N_NODES);

    f32x4 acc[2][4] = {};

    // B staging map: n = tid>>2, 16B piece = tid&3
    int bn = tid >> 2, bp = (tid & 3) * 8;

    for (int k0 = ks; k0 < ke; k0 += 32) {
        // ---- stage A: 128 rows x 32 k fp32 -> hi/lo bf16 ----
#pragma unroll
        for (int i = 0; i < 4; i++) {
            int f = tid + i * 256;
            int row = f >> 3, kq = f & 7;
            int gm = m0 + row, gk = k0 + kq * 4;
            float4 v = make_float4(0.f, 0.f, 0.f, 0.f);
            if (gm < N_NODES && gk < N_NODES)
                v = *(const float4*)(x + (long)gm * N_NODES + gk);
            ushort h0 = f2bf(v.x), h1 = f2bf(v.y), h2 = f2bf(v.z), h3 = f2bf(v.w);
            ushort l0 = f2bf(v.x - bf2f(h0)), l1 = f2bf(v.y - bf2f(h1));
            ushort l2 = f2bf(v.z - bf2f(h2)), l3 = f2bf(v.w - bf2f(h3));
            *(ushort4*)&As[0][row][kq * 4] = make_ushort4(h0, h1, h2, h3);
            *(ushort4*)&As[1][row][kq * 4] = make_ushort4(l0, l1, l2, l3);
        }
        // ---- stage B: 64 n x 32 k bf16 hi/lo (pre-split, transposed) ----
        *(float4*)&Bs[0][bn][bp] = *(const float4*)&Whi[(long)bn * KP + k0 + bp];
        *(float4*)&Bs[1][bn][bp] = *(const float4*)&Wlo[(long)bn * KP + k0 + bp];
        __syncthreads();

        // ---- fragments ----
        bf16x8 ah[2], al[2], bh[4], bl[4];
#pragma unroll
        for (int r = 0; r < 2; r++) {
            int row = wv * 32 + r * 16 + lm;
            ah[r] = *(const bf16x8*)&As[0][row][q8];
            al[r] = *(const bf16x8*)&As[1][row][q8];
        }
#pragma unroll
        for (int c = 0; c < 4; c++) {
            int n = c * 16 + lm;
            bh[c] = *(const bf16x8*)&Bs[0][n][q8];
            bl[c] = *(const bf16x8*)&Bs[1][n][q8];
        }
#pragma unroll
        for (int r = 0; r < 2; r++)
#pragma unroll
            for (int c = 0; c < 4; c++) {
                acc[r][c] = __builtin_amdgcn_mfma_f32_16x16x32_bf16(al[r], bh[c], acc[r][c], 0, 0, 0);
                acc[r][c] = __builtin_amdgcn_mfma_f32_16x16x32_bf16(ah[r], bl[c], acc[r][c], 0, 0, 0);
                acc[r][c] = __builtin_amdgcn_mfma_f32_16x16x32_bf16(ah[r], bh[c], acc[r][c], 0, 0, 0);
            }
        __syncthreads();
    }

    // ---- epilogue: C/D layout col=lane&15, row=quad*4+i ----
#pragma unroll
    for (int r = 0; r < 2; r++)
#pragma unroll
        for (int c = 0; c < 4; c++) {
            int row0 = m0 + wv * 32 + r * 16 + quad * 4;
            int cn = c * 16 + lm;
#pragma unroll
            for (int i = 0; i < 4; i++) {
                int gm = row0 + i;
                if (gm < N_NODES) atomicAdd(&out[gm * 64 + cn], acc[r][c][i]);
            }
        }
}

// ---------------- small GEMMs ----------------

__global__ void k_gemm64(const float* __restrict__ in, const float* __restrict__ W,
                         float* __restrict__ out) {
    __shared__ float Ws[64 * 64];
    __shared__ float Ain[4][64];
    int tid = threadIdx.x;
    int tx = tid & 63, ty = tid >> 6;
    for (int f = tid; f < 1024; f += 256)
        *(float4*)&Ws[f * 4] = *(const float4*)&W[f * 4];
    int gm = blockIdx.x * 4 + ty;
    Ain[ty][tx] = in[gm * 64 + tx];
    __syncthreads();
    float acc = 0.f;
#pragma unroll
    for (int k = 0; k < 64; k++) acc = fmaf(Ain[ty][k], Ws[k * 64 + tx], acc);
    out[gm * 64 + tx] = acc;
}

__global__ void k_gemm16(const float* __restrict__ in, const float* __restrict__ W,
                         float* __restrict__ out) {
    __shared__ float Ws[64 * 16];
    __shared__ float Ain[16][64];
    int tid = threadIdx.x;
    int tx = tid & 15, ty = tid >> 4;
    *(float4*)&Ws[tid * 4] = *(const float4*)&W[tid * 4];
    {
        int r = tid >> 4, kq = tid & 15;
        *(float4*)&Ain[r][kq * 4] =
            *(const float4*)(in + (long)(blockIdx.x * 16 + r) * 64 + kq * 4);
    }
    __syncthreads();
    float acc = 0.f;
#pragma unroll
    for (int k = 0; k < 64; k++) acc = fmaf(Ain[ty][k], Ws[k * 16 + tx], acc);
    out[(blockIdx.x * 16 + ty) * 16 + tx] = acc;
}

// ---------------- aggregation (one wave per node, 64 cols), 4x unrolled gather ----------------

__global__ void k_agg64(const float* __restrict__ h, const float* __restrict__ bias,
                        const int* __restrict__ roff, const int* __restrict__ csrc,
                        const float* __restrict__ cw, const float* __restrict__ dinv,
                        float* __restrict__ out, int do_relu) {
    int n = blockIdx.x * 4 + (threadIdx.x >> 6);
    int c = threadIdx.x & 63;
    float di = dinv[n];
    float acc = di * di * h[n * 64 + c];  // self-loop
    int e0 = roff[n], e1 = roff[n + 1];
    int e = e0;
    for (; e + 3 < e1; e += 4) {
        int s0 = csrc[e], s1 = csrc[e + 1], s2 = csrc[e + 2], s3 = csrc[e + 3];
        float w0 = cw[e], w1 = cw[e + 1], w2 = cw[e + 2], w3 = cw[e + 3];
        float v0 = h[s0 * 64 + c], v1 = h[s1 * 64 + c];
        float v2 = h[s2 * 64 + c], v3 = h[s3 * 64 + c];
        acc = fmaf(w0, v0, acc);
        acc = fmaf(w1, v1, acc);
        acc = fmaf(w2, v2, acc);
        acc = fmaf(w3, v3, acc);
    }
    for (; e < e1; e++)
        acc = fmaf(cw[e], h[csrc[e] * 64 + c], acc);
    acc += bias[c];
    if (do_relu) acc = fmaxf(acc, 0.f);
    out[n * 64 + c] = acc;
}

// final aggregation (16 cols) + bias + softmax; one wave per node, 4 edge groups
__global__ void k_agg16_softmax(const float* __restrict__ h, const float* __restrict__ b3,
                                const int* __restrict__ roff, const int* __restrict__ csrc,
                                const float* __restrict__ cw, const float* __restrict__ dinv,
                                float* __restrict__ out) {
    int lane = threadIdx.x & 63;
    int n = blockIdx.x * 4 + (threadIdx.x >> 6);
    int c = lane & 15, g = lane >> 4;
    float di = dinv[n];
    float acc = (g == 0) ? di * di * h[n * 16 + c] : 0.f;
    int e0 = roff[n], e1 = roff[n + 1];
    for (int e = e0 + g; e < e1; e += 4)
        acc = fmaf(cw[e], h[csrc[e] * 16 + c], acc);
    acc += __shfl_xor(acc, 16);
    acc += __shfl_xor(acc, 32);
    float logit = acc + b3[c];
    float m = logit;
    m = fmaxf(m, __shfl_xor(m, 1));
    m = fmaxf(m, __shfl_xor(m, 2));
    m = fmaxf(m, __shfl_xor(m, 4));
    m = fmaxf(m, __shfl_xor(m, 8));
    float ex = expf(logit - m);
    float s = ex;
    s += __shfl_xor(s, 1);
    s += __shfl_xor(s, 2);
    s += __shfl_xor(s, 4);
    s += __shfl_xor(s, 8);
    if (g == 0) out[n * 16 + c] = ex / s;
}

// ---------------- launch ----------------

extern "C" void kernel_launch(void* const* d_in, const int* in_sizes, int n_in,
                              void* d_out, int out_size, void* d_ws, size_t ws_size,
                              hipStream_t stream) {
    (void)in_sizes; (void)n_in; (void)out_size; (void)ws_size;
    const float* x  = (const float*)d_in[0];
    const int*   ei = (const int*)d_in[1];
    const float* W1 = (const float*)d_in[2];
    const float* b1 = (const float*)d_in[3];
    const float* W2 = (const float*)d_in[4];
    const float* b2 = (const float*)d_in[5];
    const float* W3 = (const float*)d_in[6];
    const float* b3 = (const float*)d_in[7];
    float* out = (float*)d_out;
    const int* esrc = ei;
    const int* edst = ei + E_EDGES;

    char* p = (char*)d_ws;
    size_t off = 0;
    auto alloc = [&](size_t b) -> void* {
        void* r = p + off;
        off += (b + 255) & ~(size_t)255;
        return r;
    };
    int*    deg    = (int*)alloc(N_NODES * 4);
    int*    cursor = (int*)alloc(N_NODES * 4);
    int*    roff   = (int*)alloc((N_NODES + 1) * 4);
    float*  dinv   = (float*)alloc(N_NODES * 4);
    int*    csrc   = (int*)alloc(E_EDGES * 4);
    float*  cw     = (float*)alloc(E_EDGES * 4);
    float*  bufA   = (float*)alloc(N_NODES * 64 * 4);
    float*  bufB   = (float*)alloc(N_NODES * 64 * 4);
    float*  bufC   = (float*)alloc(N_NODES * 16 * 4);
    ushort* Whi    = (ushort*)alloc((size_t)64 * KP * 2);
    ushort* Wlo    = (ushort*)alloc((size_t)64 * KP * 2);

    hipMemsetAsync(deg, 0, N_NODES * 4, stream);
    hipMemsetAsync(cursor, 0, N_NODES * 4, stream);
    hipMemsetAsync(bufA, 0, N_NODES * 64 * 4, stream);  // gemm1 split-K accumulator

    k_hist<<<(E_EDGES + 255) / 256, 256, 0, stream>>>(edst, deg);
    k_dinv<<<(N_NODES + 255) / 256, 256, 0, stream>>>(deg, dinv);
    k_scan<<<1, 256, 0, stream>>>(deg, roff);
    k_scatter<<<(E_EDGES + 255) / 256, 256, 0, stream>>>(esrc, edst, roff, cursor, dinv,
                                                         csrc, cw);
    k_wsplit<<<dim3((KP + 255) / 256, 64), 256, 0, stream>>>(W1, Whi, Wlo);

    // layer 1
    k_gemm1_mfma<<<dim3((N_NODES + G1_BM - 1) / G1_BM, 8), 256, 0, stream>>>(x, Whi, Wlo, bufA);
    k_agg64<<<N_NODES / 4, 256, 0, stream>>>(bufA, b1, roff, csrc, cw, dinv, bufB, 1);
    // layer 2
    k_gemm64<<<N_NODES / 4, 256, 0, stream>>>(bufB, W2, bufA);
    k_agg64<<<N_NODES / 4, 256, 0, stream>>>(bufA, b2, roff, csrc, cw, dinv, bufB, 1);
    // layer 3 + softmax
    k_gemm16<<<N_NODES / 16, 256, 0, stream>>>(bufB, W3, bufC);
    k_agg16_softmax<<<N_NODES / 4, 256, 0, stream>>>(bufC, b3, roff, csrc, cw, dinv, out);
}

// Round 3
// 687.914 us; speedup vs baseline: 1.2441x; 1.0420x over previous
//
#include <hip/hip_runtime.h>

#define N_NODES 10000
#define E_EDGES 320000
#define KP 10016  // K padded to multiple of 32 for W split

typedef float f32x4 __attribute__((ext_vector_type(4)));
typedef __bf16 bf16x8 __attribute__((ext_vector_type(8)));

union frag_u { int4 i; bf16x8 b; };

static __device__ __forceinline__ ushort f2bf(float f) {
    unsigned u = __float_as_uint(f);
    unsigned r = (u + 0x7fffu + ((u >> 16) & 1u)) >> 16;  // RNE
    return (ushort)r;
}
static __device__ __forceinline__ float bf2f(ushort h) {
    return __uint_as_float(((unsigned)h) << 16);
}

// truncation split of two floats -> packed bf16 hi pair + lo pair (3 VALU/elem)
static __device__ __forceinline__ void split2(float f0, float f1,
                                              unsigned& hi, unsigned& lo) {
    unsigned u0 = __float_as_uint(f0), u1 = __float_as_uint(f1);
    hi = __builtin_amdgcn_perm(u1, u0, 0x07060302u);  // [f1.hi16 : f0.hi16]
    float h0 = __uint_as_float(u0 & 0xFFFF0000u);
    float h1 = __uint_as_float(u1 & 0xFFFF0000u);
    float l0 = f0 - h0, l1 = f1 - h1;  // exact residuals
    lo = __builtin_amdgcn_perm(__float_as_uint(l1), __float_as_uint(l0), 0x07060302u);
}

static __device__ __forceinline__ void load16_to_lds(const float* gp, void* lp) {
    __builtin_amdgcn_global_load_lds(
        (__attribute__((address_space(1))) void*)(gp),
        (__attribute__((address_space(3))) void*)(lp), 16, 0, 0);
}

// ---------------- degree / CSR construction ----------------

__global__ void k_hist(const int* __restrict__ dst, int* __restrict__ deg) {
    int e = blockIdx.x * blockDim.x + threadIdx.x;
    if (e < E_EDGES) atomicAdd(&deg[dst[e]], 1);
}

__global__ void k_dinv(const int* __restrict__ deg, float* __restrict__ dinv) {
    int i = blockIdx.x * blockDim.x + threadIdx.x;
    if (i < N_NODES) dinv[i] = rsqrtf(1.0f + (float)deg[i]);  // +1 self-loop
}

__global__ void k_scan(const int* __restrict__ deg, int* __restrict__ roff) {
    __shared__ int sums[256];
    __shared__ int offs[256];
    const int CH = 40;
    int t = threadIdx.x;
    int base = t * CH;
    int s = 0;
    for (int i = 0; i < CH; i++) {
        int idx = base + i;
        if (idx < N_NODES) s += deg[idx];
    }
    sums[t] = s;
    __syncthreads();
    if (t == 0) {
        int r = 0;
        for (int i = 0; i < 256; i++) { offs[i] = r; r += sums[i]; }
    }
    __syncthreads();
    int r = offs[t];
    for (int i = 0; i < CH; i++) {
        int idx = base + i;
        if (idx < N_NODES) { roff[idx] = r; r += deg[idx]; }
    }
    if (t == 255) roff[N_NODES] = E_EDGES;
}

__global__ void k_scatter(const int* __restrict__ src, const int* __restrict__ dst,
                          const int* __restrict__ roff, int* __restrict__ cursor,
                          const float* __restrict__ dinv,
                          int* __restrict__ csrc, float* __restrict__ cw) {
    int e = blockIdx.x * blockDim.x + threadIdx.x;
    if (e >= E_EDGES) return;
    int s = src[e], d = dst[e];
    int slot = roff[d] + atomicAdd(&cursor[d], 1);
    csrc[slot] = s;
    cw[slot] = dinv[s] * dinv[d];
}

// ---------------- W1 split: fp32 [10000x64] -> bf16 hi/lo transposed [64][KP] ----------------

__global__ void k_wsplit(const float* __restrict__ W1, ushort* __restrict__ Whi,
                         ushort* __restrict__ Wlo) {
    int k = blockIdx.x * 256 + threadIdx.x;
    int n = blockIdx.y;
    if (k >= KP) return;
    ushort h = 0, l = 0;
    if (k < N_NODES) {
        float f = W1[(long)k * 64 + n];
        h = f2bf(f);
        l = f2bf(f - bf2f(h));
    }
    Whi[(long)n * KP + k] = h;
    Wlo[(long)n * KP + k] = l;
}

// ---------------- GEMM1: split-bf16 MFMA, global_load_lds staging ----------------

#define G1_BM 128
#define G1_CHUNK 640
#define G1_NCHUNK 16  // 16*640 = 10240 >= KP

__global__ __launch_bounds__(256) void k_gemm1_mfma(
        const float* __restrict__ x, const ushort* __restrict__ Whi,
        const ushort* __restrict__ Wlo, float* __restrict__ out) {
    // A tile staged as raw fp32 via global_load_lds; rows of 32 floats (128 B),
    // k-pieces XOR-swizzled by (row&7) to break the 128B-stride bank pattern.
    __shared__ float As32[G1_BM][32];
    __shared__ ushort Bs[2][64][40];  // hi/lo, rows padded to 80 B (bank-friendly)

    int tid = threadIdx.x;
    int lane = tid & 63, wv = tid >> 6;
    int quad = lane >> 4, lm = lane & 15;
    int m0 = blockIdx.x * G1_BM;
    int ks = blockIdx.y * G1_CHUNK;
    int ke = min(ks + G1_CHUNK, KP);

    // per-lane source precompute for the 4 direct-to-LDS chunk loads of this wave
    int rown = lane >> 3;               // row within 8-row chunk
    int sp = (lane & 7) ^ rown;         // swizzled source k-piece
    long abase[4];
#pragma unroll
    for (int i = 0; i < 4; i++) {
        int row = (wv * 4 + i) * 8 + rown;
        int gm = min(m0 + row, N_NODES - 1);  // tail rows clamp (discarded at write)
        abase[i] = (long)gm * N_NODES + sp * 4;
    }
    const long FLAT_MAX = (long)N_NODES * N_NODES - 4;

    int bn = tid >> 2, bp = (tid & 3) * 8;
    const ushort* whip = Whi + (long)bn * KP + bp;
    const ushort* wlop = Wlo + (long)bn * KP + bp;

    f32x4 acc[2][4] = {};

    for (int k0 = ks; k0 < ke; k0 += 32) {
        // ---- A: 4x 16B/lane direct-to-LDS (wave-uniform dest base) ----
#pragma unroll
        for (int i = 0; i < 4; i++) {
            long flat = abase[i] + k0;
            if (flat > FLAT_MAX) flat = FLAT_MAX;  // k>=10000: B is zero there
            load16_to_lds(x + flat, &As32[(wv * 4 + i) * 8][0]);
        }
        // ---- B: pre-split bf16 hi/lo via registers ----
        float4 vh = *(const float4*)(whip + k0);
        float4 vl = *(const float4*)(wlop + k0);
        *(float4*)&Bs[0][bn][bp] = vh;
        *(float4*)&Bs[1][bn][bp] = vl;
        __syncthreads();

        // ---- A fragments: read swizzled fp32, truncation-split to hi/lo ----
        frag_u ah[2], al[2];
#pragma unroll
        for (int r = 0; r < 2; r++) {
            int row = wv * 32 + r * 16 + lm;
            int r7 = row & 7;
            int s0 = (quad * 2) ^ r7;
            int s1 = (quad * 2 + 1) ^ r7;
            float4 fa = *(const float4*)&As32[row][s0 * 4];  // k = quad*8 .. +4
            float4 fb = *(const float4*)&As32[row][s1 * 4];  // k = quad*8+4 .. +8
            unsigned h0, l0, h1, l1, h2, l2, h3, l3;
            split2(fa.x, fa.y, h0, l0);
            split2(fa.z, fa.w, h1, l1);
            split2(fb.x, fb.y, h2, l2);
            split2(fb.z, fb.w, h3, l3);
            ah[r].i = make_int4((int)h0, (int)h1, (int)h2, (int)h3);
            al[r].i = make_int4((int)l0, (int)l1, (int)l2, (int)l3);
        }
        frag_u bh[4], bl[4];
#pragma unroll
        for (int c = 0; c < 4; c++) {
            int n = c * 16 + lm;
            bh[c].b = *(const bf16x8*)&Bs[0][n][quad * 8];
            bl[c].b = *(const bf16x8*)&Bs[1][n][quad * 8];
        }
#pragma unroll
        for (int r = 0; r < 2; r++)
#pragma unroll
            for (int c = 0; c < 4; c++) {
                acc[r][c] = __builtin_amdgcn_mfma_f32_16x16x32_bf16(al[r].b, bh[c].b, acc[r][c], 0, 0, 0);
                acc[r][c] = __builtin_amdgcn_mfma_f32_16x16x32_bf16(ah[r].b, bl[c].b, acc[r][c], 0, 0, 0);
                acc[r][c] = __builtin_amdgcn_mfma_f32_16x16x32_bf16(ah[r].b, bh[c].b, acc[r][c], 0, 0, 0);
            }
        __syncthreads();
    }

    // ---- epilogue: C/D layout col=lane&15, row=quad*4+i ----
#pragma unroll
    for (int r = 0; r < 2; r++)
#pragma unroll
        for (int c = 0; c < 4; c++) {
            int row0 = m0 + wv * 32 + r * 16 + quad * 4;
            int cn = c * 16 + lm;
#pragma unroll
            for (int i = 0; i < 4; i++) {
                int gm = row0 + i;
                if (gm < N_NODES) atomicAdd(&out[gm * 64 + cn], acc[r][c][i]);
            }
        }
}

// ---------------- small GEMMs ----------------

__global__ void k_gemm64(const float* __restrict__ in, const float* __restrict__ W,
                         float* __restrict__ out) {
    __shared__ float Ws[64 * 64];
    __shared__ float Ain[4][64];
    int tid = threadIdx.x;
    int tx = tid & 63, ty = tid >> 6;
    for (int f = tid; f < 1024; f += 256)
        *(float4*)&Ws[f * 4] = *(const float4*)&W[f * 4];
    int gm = blockIdx.x * 4 + ty;
    Ain[ty][tx] = in[gm * 64 + tx];
    __syncthreads();
    float acc = 0.f;
#pragma unroll
    for (int k = 0; k < 64; k++) acc = fmaf(Ain[ty][k], Ws[k * 64 + tx], acc);
    out[gm * 64 + tx] = acc;
}

__global__ void k_gemm16(const float* __restrict__ in, const float* __restrict__ W,
                         float* __restrict__ out) {
    __shared__ float Ws[64 * 16];
    __shared__ float Ain[16][64];
    int tid = threadIdx.x;
    int tx = tid & 15, ty = tid >> 4;
    *(float4*)&Ws[tid * 4] = *(const float4*)&W[tid * 4];
    {
        int r = tid >> 4, kq = tid & 15;
        *(float4*)&Ain[r][kq * 4] =
            *(const float4*)(in + (long)(blockIdx.x * 16 + r) * 64 + kq * 4);
    }
    __syncthreads();
    float acc = 0.f;
#pragma unroll
    for (int k = 0; k < 64; k++) acc = fmaf(Ain[ty][k], Ws[k * 16 + tx], acc);
    out[(blockIdx.x * 16 + ty) * 16 + tx] = acc;
}

// ---------------- aggregation (one wave per node, 64 cols), 4x unrolled gather ----------------

__global__ void k_agg64(const float* __restrict__ h, const float* __restrict__ bias,
                        const int* __restrict__ roff, const int* __restrict__ csrc,
                        const float* __restrict__ cw, const float* __restrict__ dinv,
                        float* __restrict__ out, int do_relu) {
    int n = blockIdx.x * 4 + (threadIdx.x >> 6);
    int c = threadIdx.x & 63;
    float di = dinv[n];
    float acc = di * di * h[n * 64 + c];  // self-loop
    int e0 = roff[n], e1 = roff[n + 1];
    int e = e0;
    for (; e + 3 < e1; e += 4) {
        int s0 = csrc[e], s1 = csrc[e + 1], s2 = csrc[e + 2], s3 = csrc[e + 3];
        float w0 = cw[e], w1 = cw[e + 1], w2 = cw[e + 2], w3 = cw[e + 3];
        float v0 = h[s0 * 64 + c], v1 = h[s1 * 64 + c];
        float v2 = h[s2 * 64 + c], v3 = h[s3 * 64 + c];
        acc = fmaf(w0, v0, acc);
        acc = fmaf(w1, v1, acc);
        acc = fmaf(w2, v2, acc);
        acc = fmaf(w3, v3, acc);
    }
    for (; e < e1; e++)
        acc = fmaf(cw[e], h[csrc[e] * 64 + c], acc);
    acc += bias[c];
    if (do_relu) acc = fmaxf(acc, 0.f);
    out[n * 64 + c] = acc;
}

// final aggregation (16 cols) + bias + softmax; one wave per node, 4 edge groups
__global__ void k_agg16_softmax(const float* __restrict__ h, const float* __restrict__ b3,
                                const int* __restrict__ roff, const int* __restrict__ csrc,
                                const float* __restrict__ cw, const float* __restrict__ dinv,
                                float* __restrict__ out) {
    int lane = threadIdx.x & 63;
    int n = blockIdx.x * 4 + (threadIdx.x >> 6);
    int c = lane & 15, g = lane >> 4;
    float di = dinv[n];
    float acc = (g == 0) ? di * di * h[n * 16 + c] : 0.f;
    int e0 = roff[n], e1 = roff[n + 1];
    for (int e = e0 + g; e < e1; e += 4)
        acc = fmaf(cw[e], h[csrc[e] * 16 + c], acc);
    acc += __shfl_xor(acc, 16);
    acc += __shfl_xor(acc, 32);
    float logit = acc + b3[c];
    float m = logit;
    m = fmaxf(m, __shfl_xor(m, 1));
    m = fmaxf(m, __shfl_xor(m, 2));
    m = fmaxf(m, __shfl_xor(m, 4));
    m = fmaxf(m, __shfl_xor(m, 8));
    float ex = expf(logit - m);
    float s = ex;
    s += __shfl_xor(s, 1);
    s += __shfl_xor(s, 2);
    s += __shfl_xor(s, 4);
    s += __shfl_xor(s, 8);
    if (g == 0) out[n * 16 + c] = ex / s;
}

// ---------------- launch ----------------

extern "C" void kernel_launch(void* const* d_in, const int* in_sizes, int n_in,
                              void* d_out, int out_size, void* d_ws, size_t ws_size,
                              hipStream_t stream) {
    (void)in_sizes; (void)n_in; (void)out_size; (void)ws_size;
    const float* x  = (const float*)d_in[0];
    const int*   ei = (const int*)d_in[1];
    const float* W1 = (const float*)d_in[2];
    const float* b1 = (const float*)d_in[3];
    const float* W2 = (const float*)d_in[4];
    const float* b2 = (const float*)d_in[5];
    const float* W3 = (const float*)d_in[6];
    const float* b3 = (const float*)d_in[7];
    float* out = (float*)d_out;
    const int* esrc = ei;
    const int* edst = ei + E_EDGES;

    char* p = (char*)d_ws;
    size_t off = 0;
    auto alloc = [&](size_t b) -> void* {
        void* r = p + off;
        off += (b + 255) & ~(size_t)255;
        return r;
    };
    int*    deg    = (int*)alloc(N_NODES * 4);
    int*    cursor = (int*)alloc(N_NODES * 4);
    int*    roff   = (int*)alloc((N_NODES + 1) * 4);
    float*  dinv   = (float*)alloc(N_NODES * 4);
    int*    csrc   = (int*)alloc(E_EDGES * 4);
    float*  cw     = (float*)alloc(E_EDGES * 4);
    float*  bufA   = (float*)alloc(N_NODES * 64 * 4);
    float*  bufB   = (float*)alloc(N_NODES * 64 * 4);
    float*  bufC   = (float*)alloc(N_NODES * 16 * 4);
    ushort* Whi    = (ushort*)alloc((size_t)64 * KP * 2);
    ushort* Wlo    = (ushort*)alloc((size_t)64 * KP * 2);

    hipMemsetAsync(deg, 0, N_NODES * 4, stream);
    hipMemsetAsync(cursor, 0, N_NODES * 4, stream);
    hipMemsetAsync(bufA, 0, N_NODES * 64 * 4, stream);  // gemm1 split-K accumulator

    k_hist<<<(E_EDGES + 255) / 256, 256, 0, stream>>>(edst, deg);
    k_dinv<<<(N_NODES + 255) / 256, 256, 0, stream>>>(deg, dinv);
    k_scan<<<1, 256, 0, stream>>>(deg, roff);
    k_scatter<<<(E_EDGES + 255) / 256, 256, 0, stream>>>(esrc, edst, roff, cursor, dinv,
                                                         csrc, cw);
    k_wsplit<<<dim3((KP + 255) / 256, 64), 256, 0, stream>>>(W1, Whi, Wlo);

    // layer 1
    k_gemm1_mfma<<<dim3((N_NODES + G1_BM - 1) / G1_BM, G1_NCHUNK), 256, 0, stream>>>(
        x, Whi, Wlo, bufA);
    k_agg64<<<N_NODES / 4, 256, 0, stream>>>(bufA, b1, roff, csrc, cw, dinv, bufB, 1);
    // layer 2
    k_gemm64<<<N_NODES / 4, 256, 0, stream>>>(bufB, W2, bufA);
    k_agg64<<<N_NODES / 4, 256, 0, stream>>>(bufA, b2, roff, csrc, cw, dinv, bufB, 1);
    // layer 3 + softmax
    k_gemm16<<<N_NODES / 16, 256, 0, stream>>>(bufB, W3, bufC);
    k_agg16_softmax<<<N_NODES / 4, 256, 0, stream>>>(bufC, b3, roff, csrc, cw, dinv, out);
}